// Round 1
// baseline (522.062 us; speedup 1.0000x reference)
//
#include <hip/hip_runtime.h>
#include <hip/hip_bf16.h>
#include <math.h>

// Problem constants (from reference)
#define GRU_H 256
#define H1D   128
#define H2D   64
#define BB    16
#define TT    4000
#define NN    320000   // T * HOP

// ---------------- K0: zero the atomic max slots (ws is poisoned 0xAA) ----
__global__ void init_kernel(unsigned* ws_u) {
    if (threadIdx.x < 2) ws_u[threadIdx.x] = 0u;
}

// ---------------- K1: fused MLP -> ratio[B*T] ---------------------------
// One block = 64 rows. LDS-staged f32 GEMM chain, 4x8 / 4x4 register tiles.
// LDS layout (floats), total 13120 (52.5 KB):
//   phase1: Gs_c  [0,4352)   64 rows stride 68 (k-chunk of G)
//           W1s_c [4352,13056) 128 rows stride 68
//   phase2: H1s   [0,8448)   64 rows stride 132   (overlays phase1)
//           W2s_c [8448,12800) 64 rows stride 68
//   phase3: H2s   [8448,12800) 64 rows stride 68  (overlays W2s_c)
//           w3s   [12800,12864)
__global__ __launch_bounds__(256) void mlp_kernel(
    const float* __restrict__ gru, const float* __restrict__ W1,
    const float* __restrict__ b1,  const float* __restrict__ a1p,
    const float* __restrict__ W2,  const float* __restrict__ b2,
    const float* __restrict__ a2p, const float* __restrict__ W3,
    const float* __restrict__ b3,  float* __restrict__ ratio_out)
{
    __shared__ float smem[13120];
    float* Gs  = smem;
    float* W1s = smem + 4352;
    float* H1s = smem;
    float* W2s = smem + 8448;
    float* H2s = smem + 8448;
    float* w3s = smem + 12800;

    const int t  = threadIdx.x;
    const int tx = t & 15, ty = t >> 4;
    const int m0 = blockIdx.x * 64;
    const float a1v = a1p[0], a2v = a2p[0];

    // ---- layer 1: h1 = prelu(G @ W1^T + b1) ----
    float acc1[4][8];
    #pragma unroll
    for (int i = 0; i < 4; ++i)
        #pragma unroll
        for (int j = 0; j < 8; ++j) acc1[i][j] = 0.f;

    for (int kb = 0; kb < 4; ++kb) {
        const int k0 = kb * 64;
        __syncthreads();
        // stage G chunk: 64x64 -> 1024 float4
        #pragma unroll
        for (int it = 0; it < 4; ++it) {
            int idx = t + 256 * it;
            int r = idx >> 4, c4 = idx & 15;
            float4 v = *(const float4*)(gru + (size_t)(m0 + r) * GRU_H + k0 + c4 * 4);
            *(float4*)(Gs + r * 68 + c4 * 4) = v;
        }
        // stage W1 chunk: 128x64 -> 2048 float4
        #pragma unroll
        for (int it = 0; it < 8; ++it) {
            int idx = t + 256 * it;
            int o = idx >> 4, c4 = idx & 15;
            float4 v = *(const float4*)(W1 + (size_t)o * GRU_H + k0 + c4 * 4);
            *(float4*)(W1s + o * 68 + c4 * 4) = v;
        }
        __syncthreads();
        #pragma unroll
        for (int kk = 0; kk < 64; kk += 4) {
            float4 a4[4], b4[8];
            #pragma unroll
            for (int i = 0; i < 4; ++i) a4[i] = *(const float4*)(Gs + (ty + 16 * i) * 68 + kk);
            #pragma unroll
            for (int j = 0; j < 8; ++j) b4[j] = *(const float4*)(W1s + (tx + 16 * j) * 68 + kk);
            #pragma unroll
            for (int i = 0; i < 4; ++i)
                #pragma unroll
                for (int j = 0; j < 8; ++j) {
                    acc1[i][j] = fmaf(a4[i].x, b4[j].x, acc1[i][j]);
                    acc1[i][j] = fmaf(a4[i].y, b4[j].y, acc1[i][j]);
                    acc1[i][j] = fmaf(a4[i].z, b4[j].z, acc1[i][j]);
                    acc1[i][j] = fmaf(a4[i].w, b4[j].w, acc1[i][j]);
                }
        }
    }
    __syncthreads();   // everyone done reading Gs/W1s before H1s overlays them
    #pragma unroll
    for (int j = 0; j < 8; ++j) {
        const int c = tx + 16 * j;
        const float bv = b1[c];
        #pragma unroll
        for (int i = 0; i < 4; ++i) {
            float x = acc1[i][j] + bv;
            x = (x >= 0.f) ? x : a1v * x;
            H1s[(ty + 16 * i) * 132 + c] = x;
        }
    }

    // ---- layer 2: h2 = prelu(H1 @ W2^T + b2) ----
    float acc2[4][4];
    #pragma unroll
    for (int i = 0; i < 4; ++i)
        #pragma unroll
        for (int j = 0; j < 4; ++j) acc2[i][j] = 0.f;

    for (int kb = 0; kb < 2; ++kb) {
        const int k0 = kb * 64;
        __syncthreads();
        // stage W2 chunk: 64x64 -> 1024 float4
        #pragma unroll
        for (int it = 0; it < 4; ++it) {
            int idx = t + 256 * it;
            int o = idx >> 4, c4 = idx & 15;
            float4 v = *(const float4*)(W2 + (size_t)o * H1D + k0 + c4 * 4);
            *(float4*)(W2s + o * 68 + c4 * 4) = v;
        }
        __syncthreads();
        #pragma unroll
        for (int kk = 0; kk < 64; kk += 4) {
            float4 a4[4], b4[4];
            #pragma unroll
            for (int i = 0; i < 4; ++i) a4[i] = *(const float4*)(H1s + (ty + 16 * i) * 132 + k0 + kk);
            #pragma unroll
            for (int j = 0; j < 4; ++j) b4[j] = *(const float4*)(W2s + (tx + 16 * j) * 68 + kk);
            #pragma unroll
            for (int i = 0; i < 4; ++i)
                #pragma unroll
                for (int j = 0; j < 4; ++j) {
                    acc2[i][j] = fmaf(a4[i].x, b4[j].x, acc2[i][j]);
                    acc2[i][j] = fmaf(a4[i].y, b4[j].y, acc2[i][j]);
                    acc2[i][j] = fmaf(a4[i].z, b4[j].z, acc2[i][j]);
                    acc2[i][j] = fmaf(a4[i].w, b4[j].w, acc2[i][j]);
                }
        }
    }
    __syncthreads();   // done reading W2s before H2s overlays it
    #pragma unroll
    for (int j = 0; j < 4; ++j) {
        const int c = tx + 16 * j;
        const float bv = b2[c];
        #pragma unroll
        for (int i = 0; i < 4; ++i) {
            float x = acc2[i][j] + bv;
            x = (x >= 0.f) ? x : a2v * x;
            H2s[(ty + 16 * i) * 68 + c] = x;
        }
    }
    if (t < 64) w3s[t] = W3[2 * H2D + t];   // only row 2 of W3 is live
    __syncthreads();

    // ---- layer 3 (p2 only) + softplus + clip -> ratio ----
    if (t < 64) {
        float p = b3[2];
        #pragma unroll
        for (int k = 0; k < 64; ++k) p = fmaf(H2s[t * 68 + k], w3s[k], p);
        float sp = fmaxf(p, 0.f) + log1pf(expf(-fabsf(p)));   // stable softplus
        ratio_out[m0 + t] = fminf(sp + 1.0f, 20.0f);          // clip to [1,20]; sp+1 >= 1
    }
}

// ---------------- K2: block-parallel IIR compressor -> unscaled out + maxes
// Segment = 64 samples, lookback warmup = 192 (0.9^192 ~ 2e-9: seed error
// fully decayed). Uniform trip count -> no wave divergence. For n<0 the
// clamped-to-0 warmup is a fixed point (s stays g0), so t=0 region is exact.
#define SEG  64
#define LOOK 192
__global__ __launch_bounds__(256) void compress_kernel(
    const float* __restrict__ enh_g, const float* __restrict__ noi_g,
    const float* __restrict__ ratio, float* __restrict__ out,
    unsigned* __restrict__ ws_u)
{
    const int tid  = blockIdx.x * 256 + threadIdx.x;
    const int nseg = NN / SEG;               // 5000
    const bool active = tid < BB * nseg;     // 80000

    float amax_c = 0.f, amax_e = 0.f;
    if (active) {
        const int b   = tid / nseg;
        const int seg = tid - b * nseg;
        const int n0  = seg * SEG;
        const float* __restrict__ enh  = enh_g + (size_t)b * NN;
        const float* __restrict__ noi  = noi_g + (size_t)b * NN;
        const float* __restrict__ rrow = ratio + b * TT;
        float* __restrict__ orow       = out + (size_t)b * NN;

        float s_e = 0.f, s_r = 0.f;
        for (int i = 0; i < LOOK + SEG; ++i) {
            const int n  = n0 - LOOK + i;
            const int nc = n < 0 ? 0 : n;
            const float e   = enh[nc];
            const float x   = noi[nc];
            const float res = x - e;

            // linear interp of ratio at sample nc (matches reference op order)
            float src = ((float)nc + 0.5f) * 0.0125f - 0.5f;
            src = fminf(fmaxf(src, 0.f), (float)(TT - 1));
            const int   i0 = (int)src;
            const float w  = src - (float)i0;
            const int   i1 = min(i0 + 1, TT - 1);
            const float rr = rrow[i0] * (1.0f - w) + rrow[i1] * w;

            const float rcp_rr = __builtin_amdgcn_rcpf(rr);        // 1/ratio_i
            // enhanced gain, threshold 0.3
            const float env_e = fabsf(e);
            const float gr_e  = (env_e > 0.3f) ? fmaf(env_e - 0.3f, rcp_rr, 0.3f) : env_e;
            const float g_e   = fminf(fmaxf(gr_e * __builtin_amdgcn_rcpf(env_e + 1e-8f), 0.1f), 2.0f);
            // residual gain, ratio*0.5, threshold 0.1
            const float env_r = fabsf(res);
            const float gr_r  = (env_r > 0.1f) ? fmaf(env_r - 0.1f, 2.0f * rcp_rr, 0.1f) : env_r;
            const float g_r   = fminf(fmaxf(gr_r * __builtin_amdgcn_rcpf(env_r + 1e-8f), 0.1f), 2.0f);

            if (i == 0) { s_e = g_e; s_r = g_r; }
            else {
                s_e = fmaf(0.1f, g_e, 0.9f * s_e);
                s_r = fmaf(0.1f, g_r, 0.9f * s_r);
            }
            if (i >= LOOK) {                 // uniform branch across the wave
                const float c = fmaf(0.1f, res * s_r, e * s_e);
                orow[n] = c;
                amax_c = fmaxf(amax_c, fabsf(c));
                amax_e = fmaxf(amax_e, env_e);
            }
        }
    }

    // wave (64) -> block -> global max reduction
    #pragma unroll
    for (int off = 32; off > 0; off >>= 1) {
        amax_c = fmaxf(amax_c, __shfl_xor(amax_c, off, 64));
        amax_e = fmaxf(amax_e, __shfl_xor(amax_e, off, 64));
    }
    __shared__ float red[8];
    const int wave = threadIdx.x >> 6, lane = threadIdx.x & 63;
    if (lane == 0) { red[wave] = amax_c; red[4 + wave] = amax_e; }
    __syncthreads();
    if (threadIdx.x == 0) {
        float mc = fmaxf(fmaxf(red[0], red[1]), fmaxf(red[2], red[3]));
        float me = fmaxf(fmaxf(red[4], red[5]), fmaxf(red[6], red[7]));
        atomicMax(ws_u + 0, __float_as_uint(mc));   // floats >= 0: bit order == value order
        atomicMax(ws_u + 1, __float_as_uint(me));
    }
}

// ---------------- K3: in-place normalize --------------------------------
__global__ __launch_bounds__(256) void scale_kernel(float4* __restrict__ out4,
                                                    const unsigned* __restrict__ ws_u)
{
    const float mo = __uint_as_float(ws_u[0]);
    const float me = __uint_as_float(ws_u[1]);
    const float scale = me / (mo + 1e-8f);
    const size_t i = (size_t)blockIdx.x * 256 + threadIdx.x;
    float4 v = out4[i];
    v.x *= scale; v.y *= scale; v.z *= scale; v.w *= scale;
    out4[i] = v;
}

extern "C" void kernel_launch(void* const* d_in, const int* in_sizes, int n_in,
                              void* d_out, int out_size, void* d_ws, size_t ws_size,
                              hipStream_t stream) {
    const float* gru = (const float*)d_in[0];
    const float* enh = (const float*)d_in[1];
    const float* noi = (const float*)d_in[2];
    const float* W1  = (const float*)d_in[3];
    const float* b1  = (const float*)d_in[4];
    const float* a1  = (const float*)d_in[5];
    const float* W2  = (const float*)d_in[6];
    const float* b2  = (const float*)d_in[7];
    const float* a2  = (const float*)d_in[8];
    const float* W3  = (const float*)d_in[9];
    const float* b3  = (const float*)d_in[10];
    float* out = (float*)d_out;

    unsigned* ws_u = (unsigned*)d_ws;                    // [0]=max|comp|, [1]=max|enh|
    float* ratio   = (float*)((char*)d_ws + 256);        // B*T floats

    init_kernel<<<1, 64, 0, stream>>>(ws_u);
    mlp_kernel<<<(BB * TT) / 64, 256, 0, stream>>>(gru, W1, b1, a1, W2, b2, a2, W3, b3, ratio);
    compress_kernel<<<(BB * (NN / SEG) + 255) / 256, 256, 0, stream>>>(enh, noi, ratio, out, ws_u);
    scale_kernel<<<(BB * NN) / 4 / 256, 256, 0, stream>>>((float4*)out, ws_u);
}

// Round 2
// 279.256 us; speedup vs baseline: 1.8695x; 1.8695x over previous
//
#include <hip/hip_runtime.h>
#include <hip/hip_bf16.h>
#include <math.h>

// Problem constants (from reference)
#define GRU_H 256
#define H1D   128
#define H2D   64
#define BB    16
#define TT    4000
#define NN    320000   // T * HOP

// ---------------- K0: zero the atomic max slots (ws is poisoned 0xAA) ----
__global__ void init_kernel(unsigned* ws_u) {
    if (threadIdx.x < 2) ws_u[threadIdx.x] = 0u;
}

// ---------------- K1: fused MLP -> ratio[B*T] ---------------------------
// (unchanged from R1 — one change at a time; compress is 70% of runtime)
__global__ __launch_bounds__(256) void mlp_kernel(
    const float* __restrict__ gru, const float* __restrict__ W1,
    const float* __restrict__ b1,  const float* __restrict__ a1p,
    const float* __restrict__ W2,  const float* __restrict__ b2,
    const float* __restrict__ a2p, const float* __restrict__ W3,
    const float* __restrict__ b3,  float* __restrict__ ratio_out)
{
    __shared__ float smem[13120];
    float* Gs  = smem;
    float* W1s = smem + 4352;
    float* H1s = smem;
    float* W2s = smem + 8448;
    float* H2s = smem + 8448;
    float* w3s = smem + 12800;

    const int t  = threadIdx.x;
    const int tx = t & 15, ty = t >> 4;
    const int m0 = blockIdx.x * 64;
    const float a1v = a1p[0], a2v = a2p[0];

    float acc1[4][8];
    #pragma unroll
    for (int i = 0; i < 4; ++i)
        #pragma unroll
        for (int j = 0; j < 8; ++j) acc1[i][j] = 0.f;

    for (int kb = 0; kb < 4; ++kb) {
        const int k0 = kb * 64;
        __syncthreads();
        #pragma unroll
        for (int it = 0; it < 4; ++it) {
            int idx = t + 256 * it;
            int r = idx >> 4, c4 = idx & 15;
            float4 v = *(const float4*)(gru + (size_t)(m0 + r) * GRU_H + k0 + c4 * 4);
            *(float4*)(Gs + r * 68 + c4 * 4) = v;
        }
        #pragma unroll
        for (int it = 0; it < 8; ++it) {
            int idx = t + 256 * it;
            int o = idx >> 4, c4 = idx & 15;
            float4 v = *(const float4*)(W1 + (size_t)o * GRU_H + k0 + c4 * 4);
            *(float4*)(W1s + o * 68 + c4 * 4) = v;
        }
        __syncthreads();
        #pragma unroll
        for (int kk = 0; kk < 64; kk += 4) {
            float4 a4[4], b4[8];
            #pragma unroll
            for (int i = 0; i < 4; ++i) a4[i] = *(const float4*)(Gs + (ty + 16 * i) * 68 + kk);
            #pragma unroll
            for (int j = 0; j < 8; ++j) b4[j] = *(const float4*)(W1s + (tx + 16 * j) * 68 + kk);
            #pragma unroll
            for (int i = 0; i < 4; ++i)
                #pragma unroll
                for (int j = 0; j < 8; ++j) {
                    acc1[i][j] = fmaf(a4[i].x, b4[j].x, acc1[i][j]);
                    acc1[i][j] = fmaf(a4[i].y, b4[j].y, acc1[i][j]);
                    acc1[i][j] = fmaf(a4[i].z, b4[j].z, acc1[i][j]);
                    acc1[i][j] = fmaf(a4[i].w, b4[j].w, acc1[i][j]);
                }
        }
    }
    __syncthreads();
    #pragma unroll
    for (int j = 0; j < 8; ++j) {
        const int c = tx + 16 * j;
        const float bv = b1[c];
        #pragma unroll
        for (int i = 0; i < 4; ++i) {
            float x = acc1[i][j] + bv;
            x = (x >= 0.f) ? x : a1v * x;
            H1s[(ty + 16 * i) * 132 + c] = x;
        }
    }

    float acc2[4][4];
    #pragma unroll
    for (int i = 0; i < 4; ++i)
        #pragma unroll
        for (int j = 0; j < 4; ++j) acc2[i][j] = 0.f;

    for (int kb = 0; kb < 2; ++kb) {
        const int k0 = kb * 64;
        __syncthreads();
        #pragma unroll
        for (int it = 0; it < 4; ++it) {
            int idx = t + 256 * it;
            int o = idx >> 4, c4 = idx & 15;
            float4 v = *(const float4*)(W2 + (size_t)o * H1D + k0 + c4 * 4);
            *(float4*)(W2s + o * 68 + c4 * 4) = v;
        }
        __syncthreads();
        #pragma unroll
        for (int kk = 0; kk < 64; kk += 4) {
            float4 a4[4], b4[4];
            #pragma unroll
            for (int i = 0; i < 4; ++i) a4[i] = *(const float4*)(H1s + (ty + 16 * i) * 132 + k0 + kk);
            #pragma unroll
            for (int j = 0; j < 4; ++j) b4[j] = *(const float4*)(W2s + (tx + 16 * j) * 68 + kk);
            #pragma unroll
            for (int i = 0; i < 4; ++i)
                #pragma unroll
                for (int j = 0; j < 4; ++j) {
                    acc2[i][j] = fmaf(a4[i].x, b4[j].x, acc2[i][j]);
                    acc2[i][j] = fmaf(a4[i].y, b4[j].y, acc2[i][j]);
                    acc2[i][j] = fmaf(a4[i].z, b4[j].z, acc2[i][j]);
                    acc2[i][j] = fmaf(a4[i].w, b4[j].w, acc2[i][j]);
                }
        }
    }
    __syncthreads();
    #pragma unroll
    for (int j = 0; j < 4; ++j) {
        const int c = tx + 16 * j;
        const float bv = b2[c];
        #pragma unroll
        for (int i = 0; i < 4; ++i) {
            float x = acc2[i][j] + bv;
            x = (x >= 0.f) ? x : a2v * x;
            H2s[(ty + 16 * i) * 68 + c] = x;
        }
    }
    if (t < 64) w3s[t] = W3[2 * H2D + t];
    __syncthreads();

    if (t < 64) {
        float p = b3[2];
        #pragma unroll
        for (int k = 0; k < 64; ++k) p = fmaf(H2s[t * 68 + k], w3s[k], p);
        float sp = fmaxf(p, 0.f) + log1pf(expf(-fabsf(p)));
        ratio_out[m0 + t] = fminf(sp + 1.0f, 20.0f);
    }
}

// ---------------- K2: LDS-staged block-parallel IIR compressor ----------
// Tile = 8192 samples/block (256 threads x SEG=32). LOOK=96 warmup
// (0.9^96*1.9 ~ 8e-5 seed error). All global reads coalesced float4 via LDS;
// all global writes coalesced float4 via LDS transpose of register outputs.
// LDS pad: +1 float per 32 -> inner-loop lane addressing (33*t) mod 32 is
// 2-way bank aliasing (free on gfx950 per m136).
#define SEG   32
#define LOOK  96
#define TILE  8192
#define STG   (TILE + LOOK)       // 8288 floats staged per array
#define STG4  (STG / 4)           // 2072 float4
#define RS_N  112
#define PADIDX(j) ((j) + ((j) >> 5))
#define STGP  (PADIDX(STG - 1) + 1)   // 8547

__global__ __launch_bounds__(256) void compress_kernel(
    const float* __restrict__ enh_g, const float* __restrict__ noi_g,
    const float* __restrict__ ratio, float* __restrict__ out,
    unsigned* __restrict__ ws_u)
{
    __shared__ float es[STGP];
    __shared__ float ns[STGP];
    __shared__ float rs[RS_N];

    const int b  = blockIdx.y;
    const int S0 = blockIdx.x * TILE;
    const int t  = threadIdx.x;
    const float* __restrict__ enh  = enh_g + (size_t)b * NN;
    const float* __restrict__ noi  = noi_g + (size_t)b * NN;
    const float* __restrict__ rrow = ratio + b * TT;

    // ---- stage enh/noi tile [S0-LOOK, S0+TILE) with edge clamping ----
    for (int j4 = t; j4 < STG4; j4 += 256) {
        const int f = S0 - LOOK + 4 * j4;
        float4 e4, n4;
        if (f >= 0 && f + 4 <= NN) {
            e4 = *(const float4*)(enh + f);
            n4 = *(const float4*)(noi + f);
        } else {
            const int c0 = min(max(f,     0), NN - 1);
            const int c1 = min(max(f + 1, 0), NN - 1);
            const int c2 = min(max(f + 2, 0), NN - 1);
            const int c3 = min(max(f + 3, 0), NN - 1);
            e4 = make_float4(enh[c0], enh[c1], enh[c2], enh[c3]);
            n4 = make_float4(noi[c0], noi[c1], noi[c2], noi[c3]);
        }
        const int j = 4 * j4;
        es[PADIDX(j)]     = e4.x; es[PADIDX(j + 1)] = e4.y;
        es[PADIDX(j + 2)] = e4.z; es[PADIDX(j + 3)] = e4.w;
        ns[PADIDX(j)]     = n4.x; ns[PADIDX(j + 1)] = n4.y;
        ns[PADIDX(j + 2)] = n4.z; ns[PADIDX(j + 3)] = n4.w;
    }
    // ---- stage live ratio window ----
    int base_r = (int)floorf(((float)(S0 - LOOK) + 0.5f) * 0.0125f - 0.5f) - 1;
    if (base_r < 0) base_r = 0;
    if (t < RS_N) rs[t] = rrow[min(base_r + t, TT - 1)];
    __syncthreads();

    // ---- per-thread IIR over [seg0-LOOK, seg0+SEG) ----
    float c[SEG];
    float amax_c = 0.f, amax_e = 0.f;
    const int seg0   = S0 + SEG * t;
    const bool active = seg0 < NN;
    if (active) {
        float s_e = 0.f, s_r = 0.f;
        const int jbase = SEG * t;

        #pragma unroll 4
        for (int i = 0; i < LOOK + SEG; ++i) {
            const int j = jbase + i;
            const float e   = es[PADIDX(j)];
            const float x   = ns[PADIDX(j)];
            const float res = x - e;

            const int n  = seg0 - LOOK + i;
            const int nc = n < 0 ? 0 : n;
            float src = fmaf((float)nc + 0.5f, 0.0125f, -0.5f);
            src = fminf(fmaxf(src, 0.f), (float)(TT - 1));
            const int   i0 = (int)src;
            const float w  = src - (float)i0;
            const int   li = i0 - base_r;
            const float r0 = rs[li], r1 = rs[li + 1];
            const float rr = r0 * (1.0f - w) + r1 * w;

            const float rcp_rr = __builtin_amdgcn_rcpf(rr);
            const float env_e = fabsf(e);
            const float gr_e  = (env_e > 0.3f) ? fmaf(env_e - 0.3f, rcp_rr, 0.3f) : env_e;
            const float g_e   = fminf(fmaxf(gr_e * __builtin_amdgcn_rcpf(env_e + 1e-8f), 0.1f), 2.0f);
            const float env_r = fabsf(res);
            const float gr_r  = (env_r > 0.1f) ? fmaf(env_r - 0.1f, 2.0f * rcp_rr, 0.1f) : env_r;
            const float g_r   = fminf(fmaxf(gr_r * __builtin_amdgcn_rcpf(env_r + 1e-8f), 0.1f), 2.0f);

            if (i == 0) { s_e = g_e; s_r = g_r; }
            else {
                s_e = fmaf(0.1f, g_e, 0.9f * s_e);
                s_r = fmaf(0.1f, g_r, 0.9f * s_r);
            }
            if (i >= LOOK) {
                const float cv = fmaf(0.1f, res * s_r, e * s_e);
                c[i - LOOK] = cv;
                amax_c = fmaxf(amax_c, fabsf(cv));
                amax_e = fmaxf(amax_e, env_e);
            }
        }
    }

    // ---- transpose outputs through LDS (reuse ns), coalesced writeout ----
    __syncthreads();                       // all warmup reads of ns done
    if (active) {
        #pragma unroll
        for (int i = 0; i < SEG; ++i) ns[PADIDX(SEG * t + i)] = c[i];
    }
    __syncthreads();
    float* __restrict__ orow = out + (size_t)b * NN;
    #pragma unroll
    for (int j4 = t; j4 < TILE / 4; j4 += 256) {
        const int j = 4 * j4;
        if (S0 + j < NN) {
            float4 v;
            v.x = ns[PADIDX(j)];     v.y = ns[PADIDX(j + 1)];
            v.z = ns[PADIDX(j + 2)]; v.w = ns[PADIDX(j + 3)];
            *(float4*)(orow + S0 + j) = v;
        }
    }

    // ---- wave (64) -> block -> global max reduction ----
    #pragma unroll
    for (int off = 32; off > 0; off >>= 1) {
        amax_c = fmaxf(amax_c, __shfl_xor(amax_c, off, 64));
        amax_e = fmaxf(amax_e, __shfl_xor(amax_e, off, 64));
    }
    __shared__ float red[8];
    const int wave = threadIdx.x >> 6, lane = threadIdx.x & 63;
    if (lane == 0) { red[wave] = amax_c; red[4 + wave] = amax_e; }
    __syncthreads();
    if (threadIdx.x == 0) {
        float mc = fmaxf(fmaxf(red[0], red[1]), fmaxf(red[2], red[3]));
        float me = fmaxf(fmaxf(red[4], red[5]), fmaxf(red[6], red[7]));
        atomicMax(ws_u + 0, __float_as_uint(mc));
        atomicMax(ws_u + 1, __float_as_uint(me));
    }
}

// ---------------- K3: in-place normalize --------------------------------
__global__ __launch_bounds__(256) void scale_kernel(float4* __restrict__ out4,
                                                    const unsigned* __restrict__ ws_u)
{
    const float mo = __uint_as_float(ws_u[0]);
    const float me = __uint_as_float(ws_u[1]);
    const float scale = me / (mo + 1e-8f);
    const size_t i = (size_t)blockIdx.x * 256 + threadIdx.x;
    float4 v = out4[i];
    v.x *= scale; v.y *= scale; v.z *= scale; v.w *= scale;
    out4[i] = v;
}

extern "C" void kernel_launch(void* const* d_in, const int* in_sizes, int n_in,
                              void* d_out, int out_size, void* d_ws, size_t ws_size,
                              hipStream_t stream) {
    const float* gru = (const float*)d_in[0];
    const float* enh = (const float*)d_in[1];
    const float* noi = (const float*)d_in[2];
    const float* W1  = (const float*)d_in[3];
    const float* b1  = (const float*)d_in[4];
    const float* a1  = (const float*)d_in[5];
    const float* W2  = (const float*)d_in[6];
    const float* b2  = (const float*)d_in[7];
    const float* a2  = (const float*)d_in[8];
    const float* W3  = (const float*)d_in[9];
    const float* b3  = (const float*)d_in[10];
    float* out = (float*)d_out;

    unsigned* ws_u = (unsigned*)d_ws;                    // [0]=max|comp|, [1]=max|enh|
    float* ratio   = (float*)((char*)d_ws + 256);        // B*T floats

    init_kernel<<<1, 64, 0, stream>>>(ws_u);
    mlp_kernel<<<(BB * TT) / 64, 256, 0, stream>>>(gru, W1, b1, a1, W2, b2, a2, W3, b3, ratio);
    dim3 cgrid((NN + TILE - 1) / TILE, BB);              // 40 x 16
    compress_kernel<<<cgrid, 256, 0, stream>>>(enh, noi, ratio, out, ws_u);
    scale_kernel<<<(BB * NN) / 4 / 256, 256, 0, stream>>>((float4*)out, ws_u);
}

// Round 3
// 216.451 us; speedup vs baseline: 2.4119x; 1.2902x over previous
//
#include <hip/hip_runtime.h>
#include <hip/hip_bf16.h>
#include <math.h>

// Problem constants (from reference)
#define GRU_H 256
#define H1D   128
#define H2D   64
#define BB    16
#define TT    4000
#define NN    320000   // T * HOP

typedef __attribute__((ext_vector_type(8))) short short8;
typedef __attribute__((ext_vector_type(4))) float f32x4;

static __device__ __forceinline__ unsigned short f2bf(float x) {
    unsigned u = __float_as_uint(x);
    return (unsigned short)((u + 0x7FFFu + ((u >> 16) & 1u)) >> 16);
}
static __device__ __forceinline__ float bf2f(unsigned short h) {
    return __uint_as_float(((unsigned)h) << 16);
}

// ---------------- K0: zero the atomic max slots (ws is poisoned 0xAA) ----
__global__ void init_kernel(unsigned* ws_u) {
    if (threadIdx.x < 2) ws_u[threadIdx.x] = 0u;
}

// ---------------- K1: bf16-MFMA MLP -> ratio[B*T] -----------------------
// Block = 128 rows of gru_output, 256 threads = 4 waves (2x2 wave grid).
// All LDS tiles use chunked layout [kchunk][row][36] bf16: row stride 72 B
// -> bank 18*r mod 32 distinct for r=0..15 => conflict-free b64 frag reads.
// Regions (ushort units):
//   As [0,4608)  Bs [4608,9216)      (layer-1 staging, 32-k chunks)
//   h2s [0,9216)                     (overlays As/Bs after layer 1)
//   h1s [9216,27648)  = [4][128][36]
//   W2s [27648,36864) = [4][64][36]
#define H1CH 4608   // 128*36
#define W2CH 2304   // 64*36
__global__ __launch_bounds__(256) void mlp_kernel(
    const float* __restrict__ gru, const float* __restrict__ W1,
    const float* __restrict__ b1,  const float* __restrict__ a1p,
    const float* __restrict__ W2,  const float* __restrict__ b2,
    const float* __restrict__ a2p, const float* __restrict__ W3,
    const float* __restrict__ b3,  float* __restrict__ ratio_out)
{
    __shared__ unsigned short smem[36864];
    __shared__ float w3f[64];
    unsigned short* As  = smem;
    unsigned short* Bs  = smem + 4608;
    unsigned short* h2s = smem;          // overlays As/Bs (safe: after layer 1)
    unsigned short* h1s = smem + 9216;
    unsigned short* W2s = smem + 27648;

    const int t    = threadIdx.x;
    const int wave = t >> 6, lane = t & 63;
    const int lr   = lane & 15, q = lane >> 4;
    const int m0   = blockIdx.x * 128;
    const float a1v = a1p[0], a2v = a2p[0];

    if (t < 64) w3f[t] = W3[2 * H2D + t];   // only row 2 of W3 is live

    // ================= layer 1: h1 = prelu(G @ W1^T + b1) ===============
    const int wr = wave >> 1;   // 0/1 -> row offset 0/64
    const int wc = wave & 1;    // 0/1 -> col offset 0/64
    f32x4 acc1[4][4];
    #pragma unroll
    for (int mi = 0; mi < 4; ++mi)
        #pragma unroll
        for (int ni = 0; ni < 4; ++ni) acc1[mi][ni] = (f32x4){0.f, 0.f, 0.f, 0.f};

    for (int kc = 0; kc < 8; ++kc) {
        const int k0 = kc * 32;
        __syncthreads();
        // stage G chunk 128x32 and W1 chunk 128x32 (f32 -> bf16)
        #pragma unroll
        for (int it = 0; it < 4; ++it) {
            const int idx = t + 256 * it;          // 0..1023
            const int row = idx >> 3, c4 = idx & 7;
            float4 g = *(const float4*)(gru + (size_t)(m0 + row) * GRU_H + k0 + c4 * 4);
            ushort4 gh = {f2bf(g.x), f2bf(g.y), f2bf(g.z), f2bf(g.w)};
            *(ushort4*)(As + row * 36 + c4 * 4) = gh;
            float4 w = *(const float4*)(W1 + (size_t)row * GRU_H + k0 + c4 * 4);
            ushort4 wh = {f2bf(w.x), f2bf(w.y), f2bf(w.z), f2bf(w.w)};
            *(ushort4*)(Bs + row * 36 + c4 * 4) = wh;
        }
        __syncthreads();
        short8 af[4], bf[4];
        #pragma unroll
        for (int mi = 0; mi < 4; ++mi) {
            const unsigned short* p = As + (wr * 64 + mi * 16 + lr) * 36 + q * 8;
            ushort4 lo = *(const ushort4*)(p), hi = *(const ushort4*)(p + 4);
            af[mi] = (short8){(short)lo.x, (short)lo.y, (short)lo.z, (short)lo.w,
                              (short)hi.x, (short)hi.y, (short)hi.z, (short)hi.w};
        }
        #pragma unroll
        for (int ni = 0; ni < 4; ++ni) {
            const unsigned short* p = Bs + (wc * 64 + ni * 16 + lr) * 36 + q * 8;
            ushort4 lo = *(const ushort4*)(p), hi = *(const ushort4*)(p + 4);
            bf[ni] = (short8){(short)lo.x, (short)lo.y, (short)lo.z, (short)lo.w,
                              (short)hi.x, (short)hi.y, (short)hi.z, (short)hi.w};
        }
        #pragma unroll
        for (int mi = 0; mi < 4; ++mi)
            #pragma unroll
            for (int ni = 0; ni < 4; ++ni)
                acc1[mi][ni] = __builtin_amdgcn_mfma_f32_16x16x32_bf16(
                    af[mi], bf[ni], acc1[mi][ni], 0, 0, 0);
    }

    // epilogue: bias + prelu, write h1 (bf16) to chunked LDS
    #pragma unroll
    for (int ni = 0; ni < 4; ++ni) {
        const int col = wc * 64 + ni * 16 + lr;
        const float bv = b1[col];
        unsigned short* dst = h1s + (col >> 5) * H1CH + (col & 31);
        #pragma unroll
        for (int mi = 0; mi < 4; ++mi) {
            const int rbase = wr * 64 + mi * 16 + q * 4;
            #pragma unroll
            for (int r = 0; r < 4; ++r) {
                float x = acc1[mi][ni][r] + bv;
                x = (x >= 0.f) ? x : a1v * x;
                dst[(rbase + r) * 36] = f2bf(x);
            }
        }
    }
    // stage W2 (64x128, f32 -> bf16) into chunked LDS
    #pragma unroll
    for (int it = 0; it < 8; ++it) {
        const int idx = t + 256 * it;              // 0..2047
        const int row = idx >> 5, c4 = idx & 31;   // 32 float4 per row
        float4 w = *(const float4*)(W2 + (size_t)row * H1D + c4 * 4);
        ushort4 wh = {f2bf(w.x), f2bf(w.y), f2bf(w.z), f2bf(w.w)};
        *(ushort4*)(W2s + (c4 >> 3) * W2CH + row * 36 + (c4 & 7) * 4) = wh;
    }
    __syncthreads();

    // ================= layer 2: h2 = prelu(H1 @ W2^T + b2) ==============
    const int wr2 = wave >> 1;   // row offset 0/64
    const int wc2 = wave & 1;    // col offset 0/32
    f32x4 acc2[4][2];
    #pragma unroll
    for (int mi = 0; mi < 4; ++mi)
        #pragma unroll
        for (int ni = 0; ni < 2; ++ni) acc2[mi][ni] = (f32x4){0.f, 0.f, 0.f, 0.f};

    #pragma unroll
    for (int kc = 0; kc < 4; ++kc) {
        short8 af[4], bf[2];
        #pragma unroll
        for (int mi = 0; mi < 4; ++mi) {
            const unsigned short* p = h1s + kc * H1CH + (wr2 * 64 + mi * 16 + lr) * 36 + q * 8;
            ushort4 lo = *(const ushort4*)(p), hi = *(const ushort4*)(p + 4);
            af[mi] = (short8){(short)lo.x, (short)lo.y, (short)lo.z, (short)lo.w,
                              (short)hi.x, (short)hi.y, (short)hi.z, (short)hi.w};
        }
        #pragma unroll
        for (int ni = 0; ni < 2; ++ni) {
            const unsigned short* p = W2s + kc * W2CH + (wc2 * 32 + ni * 16 + lr) * 36 + q * 8;
            ushort4 lo = *(const ushort4*)(p), hi = *(const ushort4*)(p + 4);
            bf[ni] = (short8){(short)lo.x, (short)lo.y, (short)lo.z, (short)lo.w,
                              (short)hi.x, (short)hi.y, (short)hi.z, (short)hi.w};
        }
        #pragma unroll
        for (int mi = 0; mi < 4; ++mi)
            #pragma unroll
            for (int ni = 0; ni < 2; ++ni)
                acc2[mi][ni] = __builtin_amdgcn_mfma_f32_16x16x32_bf16(
                    af[mi], bf[ni], acc2[mi][ni], 0, 0, 0);
    }

    // epilogue: bias + prelu, write h2 (bf16) chunked, overlaying As/Bs
    #pragma unroll
    for (int ni = 0; ni < 2; ++ni) {
        const int col = wc2 * 32 + ni * 16 + lr;
        const float bv = b2[col];
        unsigned short* dst = h2s + (col >> 5) * H1CH + (col & 31);
        #pragma unroll
        for (int mi = 0; mi < 4; ++mi) {
            const int rbase = wr2 * 64 + mi * 16 + q * 4;
            #pragma unroll
            for (int r = 0; r < 4; ++r) {
                float x = acc2[mi][ni][r] + bv;
                x = (x >= 0.f) ? x : a2v * x;
                dst[(rbase + r) * 36] = f2bf(x);
            }
        }
    }
    __syncthreads();

    // ================= layer 3 (p2 only) + softplus + clip ==============
    if (t < 128) {
        float p = b3[2];
        #pragma unroll
        for (int k = 0; k < 64; ++k)
            p = fmaf(bf2f(h2s[(k >> 5) * H1CH + t * 36 + (k & 31)]), w3f[k], p);
        float sp = fmaxf(p, 0.f) + log1pf(expf(-fabsf(p)));   // stable softplus
        ratio_out[m0 + t] = fminf(sp + 1.0f, 20.0f);          // sp+1 >= 1
    }
}

// ---------------- K2: LDS-staged block-parallel IIR compressor ----------
// (unchanged from R2)
#define SEG   32
#define LOOK  96
#define TILE  8192
#define STG   (TILE + LOOK)
#define STG4  (STG / 4)
#define RS_N  112
#define PADIDX(j) ((j) + ((j) >> 5))
#define STGP  (PADIDX(STG - 1) + 1)

__global__ __launch_bounds__(256) void compress_kernel(
    const float* __restrict__ enh_g, const float* __restrict__ noi_g,
    const float* __restrict__ ratio, float* __restrict__ out,
    unsigned* __restrict__ ws_u)
{
    __shared__ float es[STGP];
    __shared__ float ns[STGP];
    __shared__ float rs[RS_N];

    const int b  = blockIdx.y;
    const int S0 = blockIdx.x * TILE;
    const int t  = threadIdx.x;
    const float* __restrict__ enh  = enh_g + (size_t)b * NN;
    const float* __restrict__ noi  = noi_g + (size_t)b * NN;
    const float* __restrict__ rrow = ratio + b * TT;

    for (int j4 = t; j4 < STG4; j4 += 256) {
        const int f = S0 - LOOK + 4 * j4;
        float4 e4, n4;
        if (f >= 0 && f + 4 <= NN) {
            e4 = *(const float4*)(enh + f);
            n4 = *(const float4*)(noi + f);
        } else {
            const int c0 = min(max(f,     0), NN - 1);
            const int c1 = min(max(f + 1, 0), NN - 1);
            const int c2 = min(max(f + 2, 0), NN - 1);
            const int c3 = min(max(f + 3, 0), NN - 1);
            e4 = make_float4(enh[c0], enh[c1], enh[c2], enh[c3]);
            n4 = make_float4(noi[c0], noi[c1], noi[c2], noi[c3]);
        }
        const int j = 4 * j4;
        es[PADIDX(j)]     = e4.x; es[PADIDX(j + 1)] = e4.y;
        es[PADIDX(j + 2)] = e4.z; es[PADIDX(j + 3)] = e4.w;
        ns[PADIDX(j)]     = n4.x; ns[PADIDX(j + 1)] = n4.y;
        ns[PADIDX(j + 2)] = n4.z; ns[PADIDX(j + 3)] = n4.w;
    }
    int base_r = (int)floorf(((float)(S0 - LOOK) + 0.5f) * 0.0125f - 0.5f) - 1;
    if (base_r < 0) base_r = 0;
    if (t < RS_N) rs[t] = rrow[min(base_r + t, TT - 1)];
    __syncthreads();

    float c[SEG];
    float amax_c = 0.f, amax_e = 0.f;
    const int seg0   = S0 + SEG * t;
    const bool active = seg0 < NN;
    if (active) {
        float s_e = 0.f, s_r = 0.f;
        const int jbase = SEG * t;

        #pragma unroll 4
        for (int i = 0; i < LOOK + SEG; ++i) {
            const int j = jbase + i;
            const float e   = es[PADIDX(j)];
            const float x   = ns[PADIDX(j)];
            const float res = x - e;

            const int n  = seg0 - LOOK + i;
            const int nc = n < 0 ? 0 : n;
            float src = fmaf((float)nc + 0.5f, 0.0125f, -0.5f);
            src = fminf(fmaxf(src, 0.f), (float)(TT - 1));
            const int   i0 = (int)src;
            const float w  = src - (float)i0;
            const int   li = i0 - base_r;
            const float r0 = rs[li], r1 = rs[li + 1];
            const float rr = r0 * (1.0f - w) + r1 * w;

            const float rcp_rr = __builtin_amdgcn_rcpf(rr);
            const float env_e = fabsf(e);
            const float gr_e  = (env_e > 0.3f) ? fmaf(env_e - 0.3f, rcp_rr, 0.3f) : env_e;
            const float g_e   = fminf(fmaxf(gr_e * __builtin_amdgcn_rcpf(env_e + 1e-8f), 0.1f), 2.0f);
            const float env_r = fabsf(res);
            const float gr_r  = (env_r > 0.1f) ? fmaf(env_r - 0.1f, 2.0f * rcp_rr, 0.1f) : env_r;
            const float g_r   = fminf(fmaxf(gr_r * __builtin_amdgcn_rcpf(env_r + 1e-8f), 0.1f), 2.0f);

            if (i == 0) { s_e = g_e; s_r = g_r; }
            else {
                s_e = fmaf(0.1f, g_e, 0.9f * s_e);
                s_r = fmaf(0.1f, g_r, 0.9f * s_r);
            }
            if (i >= LOOK) {
                const float cv = fmaf(0.1f, res * s_r, e * s_e);
                c[i - LOOK] = cv;
                amax_c = fmaxf(amax_c, fabsf(cv));
                amax_e = fmaxf(amax_e, env_e);
            }
        }
    }

    __syncthreads();
    if (active) {
        #pragma unroll
        for (int i = 0; i < SEG; ++i) ns[PADIDX(SEG * t + i)] = c[i];
    }
    __syncthreads();
    float* __restrict__ orow = out + (size_t)b * NN;
    #pragma unroll
    for (int j4 = t; j4 < TILE / 4; j4 += 256) {
        const int j = 4 * j4;
        if (S0 + j < NN) {
            float4 v;
            v.x = ns[PADIDX(j)];     v.y = ns[PADIDX(j + 1)];
            v.z = ns[PADIDX(j + 2)]; v.w = ns[PADIDX(j + 3)];
            *(float4*)(orow + S0 + j) = v;
        }
    }

    #pragma unroll
    for (int off = 32; off > 0; off >>= 1) {
        amax_c = fmaxf(amax_c, __shfl_xor(amax_c, off, 64));
        amax_e = fmaxf(amax_e, __shfl_xor(amax_e, off, 64));
    }
    __shared__ float red[8];
    const int wave = threadIdx.x >> 6, lane = threadIdx.x & 63;
    if (lane == 0) { red[wave] = amax_c; red[4 + wave] = amax_e; }
    __syncthreads();
    if (threadIdx.x == 0) {
        float mc = fmaxf(fmaxf(red[0], red[1]), fmaxf(red[2], red[3]));
        float me = fmaxf(fmaxf(red[4], red[5]), fmaxf(red[6], red[7]));
        atomicMax(ws_u + 0, __float_as_uint(mc));
        atomicMax(ws_u + 1, __float_as_uint(me));
    }
}

// ---------------- K3: in-place normalize --------------------------------
__global__ __launch_bounds__(256) void scale_kernel(float4* __restrict__ out4,
                                                    const unsigned* __restrict__ ws_u)
{
    const float mo = __uint_as_float(ws_u[0]);
    const float me = __uint_as_float(ws_u[1]);
    const float scale = me / (mo + 1e-8f);
    const size_t i = (size_t)blockIdx.x * 256 + threadIdx.x;
    float4 v = out4[i];
    v.x *= scale; v.y *= scale; v.z *= scale; v.w *= scale;
    out4[i] = v;
}

extern "C" void kernel_launch(void* const* d_in, const int* in_sizes, int n_in,
                              void* d_out, int out_size, void* d_ws, size_t ws_size,
                              hipStream_t stream) {
    const float* gru = (const float*)d_in[0];
    const float* enh = (const float*)d_in[1];
    const float* noi = (const float*)d_in[2];
    const float* W1  = (const float*)d_in[3];
    const float* b1  = (const float*)d_in[4];
    const float* a1  = (const float*)d_in[5];
    const float* W2  = (const float*)d_in[6];
    const float* b2  = (const float*)d_in[7];
    const float* a2  = (const float*)d_in[8];
    const float* W3  = (const float*)d_in[9];
    const float* b3  = (const float*)d_in[10];
    float* out = (float*)d_out;

    unsigned* ws_u = (unsigned*)d_ws;                    // [0]=max|comp|, [1]=max|enh|
    float* ratio   = (float*)((char*)d_ws + 256);        // B*T floats

    init_kernel<<<1, 64, 0, stream>>>(ws_u);
    mlp_kernel<<<(BB * TT) / 128, 256, 0, stream>>>(gru, W1, b1, a1, W2, b2, a2, W3, b3, ratio);
    dim3 cgrid((NN + TILE - 1) / TILE, BB);              // 40 x 16
    compress_kernel<<<cgrid, 256, 0, stream>>>(enh, noi, ratio, out, ws_u);
    scale_kernel<<<(BB * NN) / 4 / 256, 256, 0, stream>>>((float4*)out, ws_u);
}

// Round 4
// 189.577 us; speedup vs baseline: 2.7538x; 1.1418x over previous
//
#include <hip/hip_runtime.h>
#include <hip/hip_bf16.h>
#include <math.h>

// Problem constants (from reference)
#define GRU_H 256
#define H1D   128
#define H2D   64
#define BB    16
#define TT    4000
#define NN    320000   // T * HOP

typedef __attribute__((ext_vector_type(8))) short short8;
typedef __attribute__((ext_vector_type(4))) float f32x4;

static __device__ __forceinline__ unsigned short f2bf(float x) {
    unsigned u = __float_as_uint(x);
    return (unsigned short)((u + 0x7FFFu + ((u >> 16) & 1u)) >> 16);
}
static __device__ __forceinline__ float bf2f(unsigned short h) {
    return __uint_as_float(((unsigned)h) << 16);
}

// ---------------- K1: bf16-MFMA MLP -> ratio[B*T] -----------------------
// (unchanged from R3 except: block 0 also zeroes the ws atomic-max slots,
// replacing the separate init_kernel dispatch)
#define H1CH 4608   // 128*36
#define W2CH 2304   // 64*36
__global__ __launch_bounds__(256) void mlp_kernel(
    const float* __restrict__ gru, const float* __restrict__ W1,
    const float* __restrict__ b1,  const float* __restrict__ a1p,
    const float* __restrict__ W2,  const float* __restrict__ b2,
    const float* __restrict__ a2p, const float* __restrict__ W3,
    const float* __restrict__ b3,  float* __restrict__ ratio_out,
    unsigned* __restrict__ ws_u)
{
    __shared__ unsigned short smem[36864];
    __shared__ float w3f[64];
    unsigned short* As  = smem;
    unsigned short* Bs  = smem + 4608;
    unsigned short* h2s = smem;          // overlays As/Bs (safe: after layer 1)
    unsigned short* h1s = smem + 9216;
    unsigned short* W2s = smem + 27648;

    const int t    = threadIdx.x;
    const int wave = t >> 6, lane = t & 63;
    const int lr   = lane & 15, q = lane >> 4;
    const int m0   = blockIdx.x * 128;
    const float a1v = a1p[0], a2v = a2p[0];

    if (blockIdx.x == 0 && t < 2) ws_u[t] = 0u;   // init for compress atomics
    if (t < 64) w3f[t] = W3[2 * H2D + t];         // only row 2 of W3 is live

    // ================= layer 1: h1 = prelu(G @ W1^T + b1) ===============
    const int wr = wave >> 1;
    const int wc = wave & 1;
    f32x4 acc1[4][4];
    #pragma unroll
    for (int mi = 0; mi < 4; ++mi)
        #pragma unroll
        for (int ni = 0; ni < 4; ++ni) acc1[mi][ni] = (f32x4){0.f, 0.f, 0.f, 0.f};

    for (int kc = 0; kc < 8; ++kc) {
        const int k0 = kc * 32;
        __syncthreads();
        #pragma unroll
        for (int it = 0; it < 4; ++it) {
            const int idx = t + 256 * it;
            const int row = idx >> 3, c4 = idx & 7;
            float4 g = *(const float4*)(gru + (size_t)(m0 + row) * GRU_H + k0 + c4 * 4);
            ushort4 gh = {f2bf(g.x), f2bf(g.y), f2bf(g.z), f2bf(g.w)};
            *(ushort4*)(As + row * 36 + c4 * 4) = gh;
            float4 w = *(const float4*)(W1 + (size_t)row * GRU_H + k0 + c4 * 4);
            ushort4 wh = {f2bf(w.x), f2bf(w.y), f2bf(w.z), f2bf(w.w)};
            *(ushort4*)(Bs + row * 36 + c4 * 4) = wh;
        }
        __syncthreads();
        short8 af[4], bf[4];
        #pragma unroll
        for (int mi = 0; mi < 4; ++mi) {
            const unsigned short* p = As + (wr * 64 + mi * 16 + lr) * 36 + q * 8;
            ushort4 lo = *(const ushort4*)(p), hi = *(const ushort4*)(p + 4);
            af[mi] = (short8){(short)lo.x, (short)lo.y, (short)lo.z, (short)lo.w,
                              (short)hi.x, (short)hi.y, (short)hi.z, (short)hi.w};
        }
        #pragma unroll
        for (int ni = 0; ni < 4; ++ni) {
            const unsigned short* p = Bs + (wc * 64 + ni * 16 + lr) * 36 + q * 8;
            ushort4 lo = *(const ushort4*)(p), hi = *(const ushort4*)(p + 4);
            bf[ni] = (short8){(short)lo.x, (short)lo.y, (short)lo.z, (short)lo.w,
                              (short)hi.x, (short)hi.y, (short)hi.z, (short)hi.w};
        }
        #pragma unroll
        for (int mi = 0; mi < 4; ++mi)
            #pragma unroll
            for (int ni = 0; ni < 4; ++ni)
                acc1[mi][ni] = __builtin_amdgcn_mfma_f32_16x16x32_bf16(
                    af[mi], bf[ni], acc1[mi][ni], 0, 0, 0);
    }

    #pragma unroll
    for (int ni = 0; ni < 4; ++ni) {
        const int col = wc * 64 + ni * 16 + lr;
        const float bv = b1[col];
        unsigned short* dst = h1s + (col >> 5) * H1CH + (col & 31);
        #pragma unroll
        for (int mi = 0; mi < 4; ++mi) {
            const int rbase = wr * 64 + mi * 16 + q * 4;
            #pragma unroll
            for (int r = 0; r < 4; ++r) {
                float x = acc1[mi][ni][r] + bv;
                x = (x >= 0.f) ? x : a1v * x;
                dst[(rbase + r) * 36] = f2bf(x);
            }
        }
    }
    #pragma unroll
    for (int it = 0; it < 8; ++it) {
        const int idx = t + 256 * it;
        const int row = idx >> 5, c4 = idx & 31;
        float4 w = *(const float4*)(W2 + (size_t)row * H1D + c4 * 4);
        ushort4 wh = {f2bf(w.x), f2bf(w.y), f2bf(w.z), f2bf(w.w)};
        *(ushort4*)(W2s + (c4 >> 3) * W2CH + row * 36 + (c4 & 7) * 4) = wh;
    }
    __syncthreads();

    // ================= layer 2 ==========================================
    const int wr2 = wave >> 1;
    const int wc2 = wave & 1;
    f32x4 acc2[4][2];
    #pragma unroll
    for (int mi = 0; mi < 4; ++mi)
        #pragma unroll
        for (int ni = 0; ni < 2; ++ni) acc2[mi][ni] = (f32x4){0.f, 0.f, 0.f, 0.f};

    #pragma unroll
    for (int kc = 0; kc < 4; ++kc) {
        short8 af[4], bf[2];
        #pragma unroll
        for (int mi = 0; mi < 4; ++mi) {
            const unsigned short* p = h1s + kc * H1CH + (wr2 * 64 + mi * 16 + lr) * 36 + q * 8;
            ushort4 lo = *(const ushort4*)(p), hi = *(const ushort4*)(p + 4);
            af[mi] = (short8){(short)lo.x, (short)lo.y, (short)lo.z, (short)lo.w,
                              (short)hi.x, (short)hi.y, (short)hi.z, (short)hi.w};
        }
        #pragma unroll
        for (int ni = 0; ni < 2; ++ni) {
            const unsigned short* p = W2s + kc * W2CH + (wc2 * 32 + ni * 16 + lr) * 36 + q * 8;
            ushort4 lo = *(const ushort4*)(p), hi = *(const ushort4*)(p + 4);
            bf[ni] = (short8){(short)lo.x, (short)lo.y, (short)lo.z, (short)lo.w,
                              (short)hi.x, (short)hi.y, (short)hi.z, (short)hi.w};
        }
        #pragma unroll
        for (int mi = 0; mi < 4; ++mi)
            #pragma unroll
            for (int ni = 0; ni < 2; ++ni)
                acc2[mi][ni] = __builtin_amdgcn_mfma_f32_16x16x32_bf16(
                    af[mi], bf[ni], acc2[mi][ni], 0, 0, 0);
    }

    #pragma unroll
    for (int ni = 0; ni < 2; ++ni) {
        const int col = wc2 * 32 + ni * 16 + lr;
        const float bv = b2[col];
        unsigned short* dst = h2s + (col >> 5) * H1CH + (col & 31);
        #pragma unroll
        for (int mi = 0; mi < 4; ++mi) {
            const int rbase = wr2 * 64 + mi * 16 + q * 4;
            #pragma unroll
            for (int r = 0; r < 4; ++r) {
                float x = acc2[mi][ni][r] + bv;
                x = (x >= 0.f) ? x : a2v * x;
                dst[(rbase + r) * 36] = f2bf(x);
            }
        }
    }
    __syncthreads();

    // ================= layer 3 (p2 only) + softplus + clip ==============
    if (t < 128) {
        float p = b3[2];
        #pragma unroll
        for (int k = 0; k < 64; ++k)
            p = fmaf(bf2f(h2s[(k >> 5) * H1CH + t * 36 + (k & 31)]), w3f[k], p);
        float sp = fmaxf(p, 0.f) + log1pf(expf(-fabsf(p)));
        ratio_out[m0 + t] = fminf(sp + 1.0f, 20.0f);
    }
}

// ---------------- K2: wave-scan IIR compressor --------------------------
// s_t = 0.1 g_t + 0.9 s_{t-1} has constant coefficient -> Kogge-Stone scan
// over lanes needs only b-propagation with compile-time multipliers.
// Lane holds 4 consecutive samples (float4 I/O, no LDS staging). Wave chunk
// = 256 samples; segment = 5 stored chunks (1280) + 1 warmup chunk
// (0.9^256 ~ 1.9e-12 seed decay). Exact s_0 = g_0 via carry override at
// global sample 0. 250 segs/row * 16 rows = 4000 waves = 1000 blocks.
#define CH     256
#define SEGCH  5
#define SEGLEN (CH * SEGCH)      // 1280
#define SPR    (NN / SEGLEN)     // 250 (exact)

__global__ __launch_bounds__(256) void compress_kernel(
    const float* __restrict__ enh_g, const float* __restrict__ noi_g,
    const float* __restrict__ ratio, float* __restrict__ out,
    unsigned* __restrict__ ws_u)
{
    const int lane = threadIdx.x & 63;
    const int wid  = blockIdx.x * 4 + (threadIdx.x >> 6);   // 0..3999
    const int row  = wid / SPR;
    const int seg  = wid - row * SPR;
    const int s0   = seg * SEGLEN;

    const float* __restrict__ enh  = enh_g + (size_t)row * NN;
    const float* __restrict__ noi  = noi_g + (size_t)row * NN;
    const float* __restrict__ rrow = ratio + row * TT;
    float* __restrict__ orow       = out   + (size_t)row * NN;

    // d_lane = 0.9^(4*lane), exact bit-product (no transcendental)
    float d_lane = 1.f;
    if (lane & 1)  d_lane *= 0.65610000f;
    if (lane & 2)  d_lane *= 0.43046721f;
    if (lane & 4)  d_lane *= 0.18530202f;
    if (lane & 8)  d_lane *= 0.034336838f;
    if (lane & 16) d_lane *= 0.0011790185f;
    if (lane & 32) d_lane *= 1.3900845e-06f;

    float s_e = 0.f, s_r = 0.f;          // carry-in state (state at chunk-1 end)
    float amax_c = 0.f, amax_e = 0.f;

    for (int ci = 0; ci < SEGCH + 1; ++ci) {
        const int cb = s0 - CH + ci * CH;     // chunk base (wave-uniform)
        const int p0 = cb + 4 * lane;         // lane's first sample
        const int pc = p0 < 0 ? 0 : p0;       // clamp (only seg0 warmup)
        const float4 e4 = *(const float4*)(enh + pc);
        const float4 x4 = *(const float4*)(noi + pc);

        // ---- per-sample gains + lane-local partials (zero-init) ----
        float pe[4], pr[4];
        float ge0 = 0.f, gr0 = 0.f;
        float ae = 0.f, ar = 0.f;
        #pragma unroll
        for (int k = 0; k < 4; ++k) {
            const float e   = (&e4.x)[k];
            const float x   = (&x4.x)[k];
            const float res = x - e;
            const int n  = p0 + k;
            const int nc = n < 0 ? 0 : n;
            float src = fmaf((float)nc + 0.5f, 0.0125f, -0.5f);
            src = fminf(fmaxf(src, 0.f), 3999.f);
            const int   i0 = (int)src;
            const float w  = src - (float)i0;
            const int   i1 = min(i0 + 1, 3999);
            const float r0 = rrow[i0], r1 = rrow[i1];
            const float rr = r0 * (1.f - w) + r1 * w;
            const float rcp_rr = __builtin_amdgcn_rcpf(rr);

            const float env_e = fabsf(e);
            const float gre = (env_e > 0.3f) ? fmaf(env_e - 0.3f, rcp_rr, 0.3f) : env_e;
            const float ge  = fminf(fmaxf(gre * __builtin_amdgcn_rcpf(env_e + 1e-8f), 0.1f), 2.f);
            const float env_r = fabsf(res);
            const float grr = (env_r > 0.1f) ? fmaf(env_r - 0.1f, 2.f * rcp_rr, 0.1f) : env_r;
            const float gr  = fminf(fmaxf(grr * __builtin_amdgcn_rcpf(env_r + 1e-8f), 0.1f), 2.f);

            if (k == 0) { ge0 = ge; gr0 = gr; }
            ae = fmaf(0.9f, ae, 0.1f * ge);
            ar = fmaf(0.9f, ar, 0.1f * gr);
            pe[k] = ae; pr[k] = ar;
        }

        // ---- Kogge-Stone scan over lanes (constant-a: b-only) ----
        float Be = pe[3], Br = pr[3];
        #pragma unroll
        for (int l = 0; l < 6; ++l) {
            const int dlt = 1 << l;
            const float ml = (l == 0) ? 0.65610000f  :
                             (l == 1) ? 0.43046721f  :
                             (l == 2) ? 0.18530202f  :
                             (l == 3) ? 0.034336838f :
                             (l == 4) ? 0.0011790185f : 1.3900845e-06f;
            const float me  = (lane >= dlt) ? ml : 0.f;
            const float bse = __shfl_up(Be, dlt, 64);
            const float bsr = __shfl_up(Br, dlt, 64);
            Be = fmaf(me, bse, Be);
            Br = fmaf(me, bsr, Br);
        }
        // exclusive prefix (state before this lane, zero chunk-init part)
        float Ee = __shfl_up(Be, 1, 64); if (lane == 0) Ee = 0.f;
        float Er = __shfl_up(Br, 1, 64); if (lane == 0) Er = 0.f;

        // exact reset at global sample 0: s_0 must equal g_0
        if (cb == 0) { s_e = __shfl(ge0, 0, 64); s_r = __shfl(gr0, 0, 64); }

        // lane starting state = exclusive-local + decayed carry-in
        const float Se = fmaf(d_lane, s_e, Ee);
        const float Sr = fmaf(d_lane, s_r, Er);

        if (ci > 0) {   // stored chunk (wave-uniform branch)
            float4 o;
            #pragma unroll
            for (int k = 0; k < 4; ++k) {
                const float ck = (k == 0) ? 0.9f : (k == 1) ? 0.81f
                               : (k == 2) ? 0.729f : 0.6561f;
                const float sek = fmaf(ck, Se, pe[k]);
                const float srk = fmaf(ck, Sr, pr[k]);
                const float e   = (&e4.x)[k];
                const float res = (&x4.x)[k] - e;
                const float c   = fmaf(0.1f * res, srk, e * sek);
                (&o.x)[k] = c;
                amax_c = fmaxf(amax_c, fabsf(c));
                amax_e = fmaxf(amax_e, fabsf(e));
            }
            *(float4*)(orow + p0) = o;
        }

        // carry to next chunk: state at lane63 end = B63 + 0.9^256 * s_in
        const float b63e = __shfl(Be, 63, 64);
        const float b63r = __shfl(Br, 63, 64);
        s_e = fmaf(1.9287e-12f, s_e, b63e);
        s_r = fmaf(1.9287e-12f, s_r, b63r);
    }

    // ---- wave -> block -> global max reduction ----
    #pragma unroll
    for (int off = 32; off > 0; off >>= 1) {
        amax_c = fmaxf(amax_c, __shfl_xor(amax_c, off, 64));
        amax_e = fmaxf(amax_e, __shfl_xor(amax_e, off, 64));
    }
    __shared__ float red[8];
    const int wv = threadIdx.x >> 6, ln = threadIdx.x & 63;
    if (ln == 0) { red[wv] = amax_c; red[4 + wv] = amax_e; }
    __syncthreads();
    if (threadIdx.x == 0) {
        float mc = fmaxf(fmaxf(red[0], red[1]), fmaxf(red[2], red[3]));
        float me = fmaxf(fmaxf(red[4], red[5]), fmaxf(red[6], red[7]));
        atomicMax(ws_u + 0, __float_as_uint(mc));
        atomicMax(ws_u + 1, __float_as_uint(me));
    }
}

// ---------------- K3: in-place normalize --------------------------------
__global__ __launch_bounds__(256) void scale_kernel(float4* __restrict__ out4,
                                                    const unsigned* __restrict__ ws_u)
{
    const float mo = __uint_as_float(ws_u[0]);
    const float me = __uint_as_float(ws_u[1]);
    const float scale = me / (mo + 1e-8f);
    const size_t i = (size_t)blockIdx.x * 256 + threadIdx.x;
    float4 v = out4[i];
    v.x *= scale; v.y *= scale; v.z *= scale; v.w *= scale;
    out4[i] = v;
}

extern "C" void kernel_launch(void* const* d_in, const int* in_sizes, int n_in,
                              void* d_out, int out_size, void* d_ws, size_t ws_size,
                              hipStream_t stream) {
    const float* gru = (const float*)d_in[0];
    const float* enh = (const float*)d_in[1];
    const float* noi = (const float*)d_in[2];
    const float* W1  = (const float*)d_in[3];
    const float* b1  = (const float*)d_in[4];
    const float* a1  = (const float*)d_in[5];
    const float* W2  = (const float*)d_in[6];
    const float* b2  = (const float*)d_in[7];
    const float* a2  = (const float*)d_in[8];
    const float* W3  = (const float*)d_in[9];
    const float* b3  = (const float*)d_in[10];
    float* out = (float*)d_out;

    unsigned* ws_u = (unsigned*)d_ws;                    // [0]=max|comp|, [1]=max|enh|
    float* ratio   = (float*)((char*)d_ws + 256);        // B*T floats

    mlp_kernel<<<(BB * TT) / 128, 256, 0, stream>>>(gru, W1, b1, a1, W2, b2, a2, W3, b3, ratio, ws_u);
    compress_kernel<<<(BB * (NN / SEGLEN)) / 4, 256, 0, stream>>>(enh, noi, ratio, out, ws_u);
    scale_kernel<<<(BB * NN) / 4 / 256, 256, 0, stream>>>((float4*)out, ws_u);
}